// Round 9
// baseline (339.968 us; speedup 1.0000x reference)
//
#include <hip/hip_runtime.h>
#include <hip/hip_bf16.h>

// Problem constants (fixed by the reference's setup_inputs)
#define N_NODES 10000
#define N_EDGES 4000
#define IN_CH   128
#define HOC     128   // HEADS*OUT_CH
#define OUT_CH  64
#define CHUNK   16384 // entries per counting-sort block (scale-2)
#define SEG     256   // entries per gather wave-segment (scale-2)

#define G_GEMM  625   // N_NODES/16
#define G_ZERO  512
#define G_NPTR  40    // ceil(10001/256)

__device__ __forceinline__ float bf2f(unsigned short u) {
    union { unsigned int i; float f; } v;
    v.i = ((unsigned int)u) << 16;
    return v.f;
}
__device__ __forceinline__ unsigned short f2bfu(float f) {
    union { __hip_bfloat16 h; unsigned short u; } v;
    v.h = __float2bfloat16(f);
    return v.u;
}

// load 8 consecutive float values from either fp32 or packed-bf16 storage.
__device__ __forceinline__ void load8(const void* base, size_t eoff, int isf32,
                                      float o[8]) {
    if (isf32) {
        const float4* q = (const float4*)((const float*)base + eoff);
        float4 a = q[0], b = q[1];
        o[0]=a.x; o[1]=a.y; o[2]=a.z; o[3]=a.w;
        o[4]=b.x; o[5]=b.y; o[6]=b.z; o[7]=b.w;
    } else {
        uint4 v = *(const uint4*)((const unsigned short*)base + eoff);
        const unsigned short* pv = (const unsigned short*)&v;
#pragma unroll
        for (int q = 0; q < 8; q++) o[q] = bf2f(pv[q]);
    }
}

__device__ __forceinline__ float loadS(const void* base, int i, int isf32) {
    return isf32 ? ((const float*)base)[i] : bf2f(((const unsigned short*)base)[i]);
}

// Per-wave inline dtype probe of x's first 512 bytes (L1/L2-cached; uniform
// decision per wave). 1 = fp32 storage, 0 = packed bf16.
__device__ __forceinline__ int probe_isf32(const unsigned int* __restrict__ x) {
    const int lane = threadIdx.x & 63;
    unsigned int w0 = x[lane * 2], w1 = x[lane * 2 + 1];
    int h = 0, z = 0;
    {
        unsigned int lo = w0 & 0xFFFFu;
        if (lo == 0u) z++; else if (((lo >> 7) & 0xFF) >= 0x90u) h++;
        lo = w1 & 0xFFFFu;
        if (lo == 0u) z++; else if (((lo >> 7) & 0xFF) >= 0x90u) h++;
    }
    unsigned long long bh = __ballot(h > 0);   // fp32 mantissa garbage
    unsigned long long bz = __ballot(z == 2);  // fp32 storing bf16-rounded
    return (__popcll(bh) > 8 || __popcll(bz) > 50) ? 1 : 0;
}

// ---------------------------------------------------------------------------
// MEGA-PREP: block-range fused, all roles mutually independent.
//  [0, nblk)                hist2: per-CHUNK edge histogram of idx2 -> bh
//  [nblk, nblk+8)           hist1: per-block histograms of idx1 -> bh1e/bh1n
//  [.., +G_GEMM)            gemm: xt1/xt2 = x@W1^T+b1 / x@W2^T+b2 (bf16 out)
//  [.., +G_ZERO)            zero: o + fill1e + fill1n + esum2f (grid-stride)
//  [.., +G_NPTR)            nptr: lower_bound(idx2, n)
__global__ __launch_bounds__(256) void prep(
    const void* __restrict__ x,
    const void* __restrict__ W1, const void* __restrict__ b1,
    const void* __restrict__ W2, const void* __restrict__ b2,
    unsigned short* __restrict__ xt1b, unsigned short* __restrict__ xt2b,
    const int* __restrict__ idx1, int nnz1,
    const int* __restrict__ idx2, int nnz2,
    int* __restrict__ nptr, float4* __restrict__ zerobase, int zeroN4,
    int* __restrict__ bh, int* __restrict__ bh1e, int* __restrict__ bh1n,
    int nblk)
{
    __shared__ __align__(16) char smem[40000];
    int b = blockIdx.x;

    if (b < nblk) {                     // ---- hist2 ----
        int* h = (int*)smem;
        for (int t = threadIdx.x; t < N_EDGES; t += 256) h[t] = 0;
        __syncthreads();
        const int lo = b * CHUNK;
        const int hi = min(nnz2, lo + CHUNK);
        for (int i = lo + threadIdx.x; i < hi; i += 256)
            atomicAdd(&h[idx2[nnz2 + i]], 1);
        __syncthreads();
        int* dst = bh + (size_t)b * N_EDGES;
        for (int t = threadIdx.x; t < N_EDGES; t += 256) dst[t] = h[t];
        return;
    }
    b -= nblk;

    if (b < 8) {                        // ---- hist1 (4 edge + 4 node blocks) ----
        const int isEdge = b < 4;
        const int bid = isEdge ? b : (b - 4);
        const int nb = isEdge ? N_EDGES : N_NODES;
        const int* src = isEdge ? (idx1 + nnz1) : idx1;
        int* dst = isEdge ? (bh1e + bid * N_EDGES) : (bh1n + bid * N_NODES);
        int* h = (int*)smem;
        for (int t = threadIdx.x; t < nb; t += 256) h[t] = 0;
        __syncthreads();
        for (int i = bid * 256 + threadIdx.x; i < nnz1; i += 4 * 256)
            atomicAdd(&h[src[i]], 1);
        __syncthreads();
        for (int t = threadIdx.x; t < nb; t += 256) dst[t] = h[t];
        return;
    }
    b -= 8;

    if (b < G_GEMM) {                   // ---- gemm ----
        const int isf32 = probe_isf32((const unsigned int*)x);
        float (*xs)[IN_CH] = (float (*)[IN_CH])smem;
        const int n0 = b * 16;
        {
            float v[8];
            load8(x, (size_t)n0 * IN_CH + (size_t)threadIdx.x * 8, isf32, v);
            float* dst = &xs[0][0] + threadIdx.x * 8;
#pragma unroll
            for (int q = 0; q < 8; q++) dst[q] = v[q];
        }
        __syncthreads();

        const int sel = threadIdx.x >> 7;
        const int j   = threadIdx.x & 127;
        const void* W  = sel ? W2 : W1;
        const void* bb = sel ? b2 : b1;
        unsigned short* xt = sel ? xt2b : xt1b;

        float acc[16];
#pragma unroll
        for (int m = 0; m < 16; m++) acc[m] = 0.f;

        for (int kk = 0; kk < 16; kk++) {
            float w[8];
            load8(W, (size_t)j * IN_CH + kk * 8, isf32, w);
#pragma unroll
            for (int m = 0; m < 16; m++) {
                const float* xr = &xs[m][kk * 8];
                acc[m] += xr[0]*w[0] + xr[1]*w[1] + xr[2]*w[2] + xr[3]*w[3]
                        + xr[4]*w[4] + xr[5]*w[5] + xr[6]*w[6] + xr[7]*w[7];
            }
        }
        const float bias = loadS(bb, j, isf32);
#pragma unroll
        for (int m = 0; m < 16; m++)
            xt[(size_t)(n0 + m) * HOC + j] = f2bfu(acc[m] + bias);
        return;
    }
    b -= G_GEMM;

    if (b < G_ZERO) {                   // ---- zero (grid-stride float4) ----
        for (int t = b * 256 + threadIdx.x; t < zeroN4; t += G_ZERO * 256)
            zerobase[t] = make_float4(0.f, 0.f, 0.f, 0.f);
        return;
    }
    b -= G_ZERO;

    {                                   // ---- nptr ----
        int n = b * 256 + threadIdx.x;
        if (n > N_NODES) return;
        int lo = 0, hi = nnz2;
        while (lo < hi) { int mid = (lo + hi) >> 1; if (idx2[mid] < n) lo = mid + 1; else hi = mid; }
        nptr[n] = lo;
    }
}

// ---------------------------------------------------------------------------
// 3-block scan kernel: derives cnt from per-block hists, writes exclusive ptrs.
//  block 0: ptr2 from bh columns; block 1: ptr1e from bh1e; block 2: ptr1n.
__global__ __launch_bounds__(256) void scans3(
    const int* __restrict__ bh, int nblk, int* __restrict__ ptr2,
    const int* __restrict__ bh1e, int* __restrict__ ptr1e,
    const int* __restrict__ bh1n, int* __restrict__ ptr1n)
{
    __shared__ int buf[10240];
    __shared__ int part[256];
    const int t = threadIdx.x;
    int nb; const int* src; int ncol, colstride; int* ptr;
    if (blockIdx.x == 0)      { nb = N_EDGES; src = bh;   ncol = nblk; colstride = N_EDGES; ptr = ptr2; }
    else if (blockIdx.x == 1) { nb = N_EDGES; src = bh1e; ncol = 4;    colstride = N_EDGES; ptr = ptr1e; }
    else                      { nb = N_NODES; src = bh1n; ncol = 4;    colstride = N_NODES; ptr = ptr1n; }
    const int K = (nb + 255) >> 8;
    const int base = t * K;
    int s = 0;
    for (int q = 0; q < K; q++) {
        int i = base + q;
        int v = 0;
        if (i < nb)
            for (int k = 0; k < ncol; k++) v += src[(size_t)k * colstride + i];
        buf[t * K + q] = v;
        s += v;
    }
    part[t] = s;
    __syncthreads();
    for (int d = 1; d < 256; d <<= 1) {
        int v = (t >= d) ? part[t - d] : 0;
        __syncthreads();
        part[t] += v;
        __syncthreads();
    }
    int run = part[t] - s;
    for (int q = 0; q < K; q++) {
        int i = base + q;
        if (i < nb) { ptr[i] = run; run += buf[t * K + q]; }
    }
    if (t == 255) ptr[nb] = part[255];
}

// ---------------------------------------------------------------------------
// Fused: scan_blocks (bh counts -> per-block bases) + fill_both (scale-1 lists)
__global__ __launch_bounds__(256) void sb_fb(
    const int* __restrict__ ptr2, int* __restrict__ bh, int nblk,
    const int* __restrict__ idx1, int nnz1,
    const int* __restrict__ ptr1e, int* __restrict__ fill1e,
    unsigned short* __restrict__ nodelist1,
    const int* __restrict__ ptr1n, int* __restrict__ fill1n,
    unsigned short* __restrict__ edgelist1)
{
    int b = blockIdx.x;
    if (b < 16) {                       // scan_blocks: thread per edge
        int e = b * 256 + threadIdx.x;
        if (e >= N_EDGES) return;
        int run = ptr2[e];
        for (int k = 0; k < nblk; k++) {
            int i = k * N_EDGES + e;
            int t = bh[i];
            bh[i] = run;
            run += t;
        }
        return;
    }
    b -= 16;
    int i = b * 256 + threadIdx.x;
    if (i >= nnz1) return;
    int n = idx1[i];
    int e = idx1[nnz1 + i];
    int se = atomicAdd(&fill1e[e], 1);
    nodelist1[ptr1e[e] + se] = (unsigned short)n;
    int sn = atomicAdd(&fill1n[n], 1);
    edgelist1[ptr1n[n] + sn] = (unsigned short)e;
}

// ---------------------------------------------------------------------------
// scale-2 placement with LDS slot counters (no global atomics)
__global__ __launch_bounds__(256) void place_entries(
    const int* __restrict__ idx, int nnz, const int* __restrict__ bh,
    unsigned short* __restrict__ nodelist)
{
    __shared__ int lh[N_EDGES];
    for (int t = threadIdx.x; t < N_EDGES; t += 256) lh[t] = 0;
    __syncthreads();
    const int b = blockIdx.x;
    const int lo = b * CHUNK;
    const int hi = min(nnz, lo + CHUNK);
    const int* bhb = bh + (size_t)b * N_EDGES;
    for (int i = lo + threadIdx.x; i < hi; i += 256) {
        int n = idx[i];
        int e = idx[nnz + i];
        int s = atomicAdd(&lh[e], 1);
        nodelist[bhb[e] + s] = (unsigned short)n;
    }
}

// ---------------------------------------------------------------------------
// Fused edge gathers:
//  [0, segB): scale-2 segment-parallel sum into esum2f (8-wide ILP + flush)
//  [segB, segB+1000): scale-1 wave-per-edge mean (fused div+pack)
__global__ __launch_bounds__(256) void edge_gather(
    const unsigned short* __restrict__ nodelist2, const int* __restrict__ ptr2,
    int nnz2, const unsigned int* __restrict__ xt2u, float* __restrict__ esum2f,
    int segB,
    const unsigned short* __restrict__ nodelist1, const int* __restrict__ ptr1e,
    const unsigned int* __restrict__ xt1u, unsigned int* __restrict__ emean1u)
{
    const int lane = threadIdx.x & 63;
    int b = blockIdx.x;
    if (b < segB) {
        const int wave = (b * 256 + threadIdx.x) >> 6;
        const int s = wave * SEG;
        if (s >= nnz2) return;
        const int e_end = min(nnz2, s + SEG);
        int lo = 0, hi = N_EDGES;
        while (lo < hi) { int mid = (lo + hi) >> 1; if (ptr2[mid] <= s) lo = mid + 1; else hi = mid; }
        int g = lo - 1;
        int next = ptr2[g + 1];
        float accx = 0.f, accy = 0.f;
        for (int i = s; i < e_end; i += 64) {
            const int m = min(64, e_end - i);
            int vl = (i + lane < e_end) ? (int)nodelist2[i + lane] : 0;
            int j = 0;
            while (j < m) {
                while (i + j >= next) {
                    unsafeAtomicAdd(esum2f + (size_t)g * HOC + 2 * lane,     accx);
                    unsafeAtomicAdd(esum2f + (size_t)g * HOC + 2 * lane + 1, accy);
                    accx = accy = 0.f;
                    g++;
                    next = ptr2[g + 1];
                }
                int run = min(m - j, next - (i + j));
                int t = 0;
                for (; t + 7 < run; t += 8) {
                    int nn[8]; unsigned int uu[8];
#pragma unroll
                    for (int q = 0; q < 8; q++) nn[q] = __shfl(vl, j + t + q);
#pragma unroll
                    for (int q = 0; q < 8; q++) uu[q] = xt2u[nn[q] * 64 + lane];
#pragma unroll
                    for (int q = 0; q < 8; q++) {
                        accx += bf2f((unsigned short)(uu[q] & 0xFFFFu));
                        accy += bf2f((unsigned short)(uu[q] >> 16));
                    }
                }
                for (; t < run; t++) {
                    int n = __shfl(vl, j + t);
                    unsigned int u = xt2u[n * 64 + lane];
                    accx += bf2f((unsigned short)(u & 0xFFFFu));
                    accy += bf2f((unsigned short)(u >> 16));
                }
                j += run;
            }
        }
        unsafeAtomicAdd(esum2f + (size_t)g * HOC + 2 * lane,     accx);
        unsafeAtomicAdd(esum2f + (size_t)g * HOC + 2 * lane + 1, accy);
        return;
    }
    b -= segB;
    {   // scale-1 wave-per-edge mean
        const int e = b * 4 + (threadIdx.x >> 6);
        const int lo = ptr1e[e], hi = ptr1e[e + 1];
        float accx = 0.f, accy = 0.f;
        for (int base = lo; base < hi; base += 64) {
            const int m = min(64, hi - base);
            int vl = (base + lane < hi) ? (int)nodelist1[base + lane] : 0;
            int t = 0;
            for (; t + 7 < m; t += 8) {
                int nn[8]; unsigned int uu[8];
#pragma unroll
                for (int q = 0; q < 8; q++) nn[q] = __shfl(vl, t + q);
#pragma unroll
                for (int q = 0; q < 8; q++) uu[q] = xt1u[nn[q] * 64 + lane];
#pragma unroll
                for (int q = 0; q < 8; q++) {
                    accx += bf2f((unsigned short)(uu[q] & 0xFFFFu));
                    accy += bf2f((unsigned short)(uu[q] >> 16));
                }
            }
            for (; t < m; t++) {
                int n = __shfl(vl, t);
                unsigned int u = xt1u[n * 64 + lane];
                accx += bf2f((unsigned short)(u & 0xFFFFu));
                accy += bf2f((unsigned short)(u >> 16));
            }
        }
        const float inv = 1.f / fmaxf((float)(hi - lo), 1.f);
        emean1u[e * 64 + lane] =
            ((unsigned int)f2bfu(accy * inv) << 16) | f2bfu(accx * inv);
    }
}

// ---------------------------------------------------------------------------
// s2 mean + pack to bf16x2 (counts derived from ptr2 diffs)
__global__ __launch_bounds__(256) void pack2(
    const float* __restrict__ esum2f, const int* __restrict__ ptr2,
    unsigned int* __restrict__ emean2u)
{
    int t = blockIdx.x * 256 + threadIdx.x;   // t < N_EDGES*64
    int e = t >> 6;
    float inv = 1.f / fmaxf((float)(ptr2[e + 1] - ptr2[e]), 1.f);
    float2 v = *(const float2*)(esum2f + (size_t)t * 2);
    emean2u[t] = ((unsigned int)f2bfu(v.y * inv) << 16) | f2bfu(v.x * inv);
}

// ---------------------------------------------------------------------------
// Fused node gathers (both sides atomically accumulate into zeroed o):
//  [0, segB): scale-2 segment-parallel; [segB, +2500): scale-1 wave-per-node.
__global__ __launch_bounds__(256) void node_gather(
    const int* __restrict__ vals2, const int* __restrict__ nptr, int nnz2,
    const unsigned int* __restrict__ emean2u, float* __restrict__ o, int segB,
    const unsigned short* __restrict__ edgelist1, const int* __restrict__ ptr1n,
    const unsigned int* __restrict__ emean1u)
{
    const int lane = threadIdx.x & 63;
    int b = blockIdx.x;
    if (b < segB) {
        const int wave = (b * 256 + threadIdx.x) >> 6;
        const int s = wave * SEG;
        if (s >= nnz2) return;
        const int e_end = min(nnz2, s + SEG);
        int lo = 0, hi = N_NODES;
        while (lo < hi) { int mid = (lo + hi) >> 1; if (nptr[mid] <= s) lo = mid + 1; else hi = mid; }
        int g = lo - 1;
        int next = nptr[g + 1];
        float accx = 0.f, accy = 0.f;
        for (int i = s; i < e_end; i += 64) {
            const int m = min(64, e_end - i);
            int vl = (i + lane < e_end) ? vals2[i + lane] : 0;
            int j = 0;
            while (j < m) {
                while (i + j >= next) {
                    unsafeAtomicAdd(o + (size_t)g * HOC + 2 * lane,     accx);
                    unsafeAtomicAdd(o + (size_t)g * HOC + 2 * lane + 1, accy);
                    accx = accy = 0.f;
                    g++;
                    next = nptr[g + 1];
                }
                int run = min(m - j, next - (i + j));
                int t = 0;
                for (; t + 7 < run; t += 8) {
                    int ee[8]; unsigned int uu[8];
#pragma unroll
                    for (int q = 0; q < 8; q++) ee[q] = __shfl(vl, j + t + q);
#pragma unroll
                    for (int q = 0; q < 8; q++) uu[q] = emean2u[ee[q] * 64 + lane];
#pragma unroll
                    for (int q = 0; q < 8; q++) {
                        accx += bf2f((unsigned short)(uu[q] & 0xFFFFu));
                        accy += bf2f((unsigned short)(uu[q] >> 16));
                    }
                }
                for (; t < run; t++) {
                    int e = __shfl(vl, j + t);
                    unsigned int u = emean2u[e * 64 + lane];
                    accx += bf2f((unsigned short)(u & 0xFFFFu));
                    accy += bf2f((unsigned short)(u >> 16));
                }
                j += run;
            }
        }
        unsafeAtomicAdd(o + (size_t)g * HOC + 2 * lane,     accx);
        unsafeAtomicAdd(o + (size_t)g * HOC + 2 * lane + 1, accy);
        return;
    }
    b -= segB;
    {   // scale-1 wave-per-node (atomic adds; concurrent with s2 part)
        const int n = b * 4 + (threadIdx.x >> 6);
        const int lo = ptr1n[n], hi = ptr1n[n + 1];
        if (lo == hi) return;
        float accx = 0.f, accy = 0.f;
        for (int base = lo; base < hi; base += 64) {
            const int m = min(64, hi - base);
            int vl = (base + lane < hi) ? (int)edgelist1[base + lane] : 0;
            int t = 0;
            for (; t + 7 < m; t += 8) {
                int ee[8]; unsigned int uu[8];
#pragma unroll
                for (int q = 0; q < 8; q++) ee[q] = __shfl(vl, t + q);
#pragma unroll
                for (int q = 0; q < 8; q++) uu[q] = emean1u[ee[q] * 64 + lane];
#pragma unroll
                for (int q = 0; q < 8; q++) {
                    accx += bf2f((unsigned short)(uu[q] & 0xFFFFu));
                    accy += bf2f((unsigned short)(uu[q] >> 16));
                }
            }
            for (; t < m; t++) {
                int e = __shfl(vl, t);
                unsigned int u = emean1u[e * 64 + lane];
                accx += bf2f((unsigned short)(u & 0xFFFFu));
                accy += bf2f((unsigned short)(u >> 16));
            }
        }
        unsafeAtomicAdd(o + (size_t)n * HOC + 2 * lane,     accx);
        unsafeAtomicAdd(o + (size_t)n * HOC + 2 * lane + 1, accy);
    }
}

// ---------------------------------------------------------------------------
// out = 0.5*o @ Wout^T + bout  (16 nodes/block; 4 indep acc chains/thread)
__global__ __launch_bounds__(256) void outproj(
    const float* __restrict__ o, const void* __restrict__ Wout,
    const void* __restrict__ bout, void* __restrict__ out,
    const unsigned int* __restrict__ xprobe)
{
    const int isf32 = probe_isf32(xprobe);
    __shared__ float os[16][HOC];
    const int n0 = blockIdx.x * 16;
    {
        const float4* src = (const float4*)(o + (size_t)n0 * HOC);
        float4* d = (float4*)&os[0][0];
        d[threadIdx.x]       = src[threadIdx.x];
        d[threadIdx.x + 256] = src[threadIdx.x + 256];
    }
    __syncthreads();
    const int jo = threadIdx.x & 63;
    const int g  = threadIdx.x >> 6;
    float acc[4] = {0.f, 0.f, 0.f, 0.f};
    for (int kk = 0; kk < 16; kk++) {
        float w[8];
        load8(Wout, (size_t)jo * HOC + kk * 8, isf32, w);
#pragma unroll
        for (int mm = 0; mm < 4; mm++) {
            const float* xr = &os[g * 4 + mm][kk * 8];
            acc[mm] += xr[0]*w[0] + xr[1]*w[1] + xr[2]*w[2] + xr[3]*w[3]
                     + xr[4]*w[4] + xr[5]*w[5] + xr[6]*w[6] + xr[7]*w[7];
        }
    }
    const float bias = loadS(bout, jo, isf32);
#pragma unroll
    for (int mm = 0; mm < 4; mm++) {
        float r = 0.5f * acc[mm] + bias;
        size_t oi = (size_t)(n0 + g * 4 + mm) * OUT_CH + jo;
        if (isf32) ((float*)out)[oi] = r;
        else       ((__hip_bfloat16*)out)[oi] = __float2bfloat16(r);
    }
}

// ---------------------------------------------------------------------------
extern "C" void kernel_launch(void* const* d_in, const int* in_sizes, int n_in,
                              void* d_out, int out_size, void* d_ws, size_t ws_size,
                              hipStream_t stream)
{
    const void* x  = d_in[0];
    const int* idx1 = (const int*)d_in[1];
    const int* idx2 = (const int*)d_in[2];
    const void* W1 = d_in[3];
    const void* b1 = d_in[4];
    const void* W2 = d_in[5];
    const void* b2 = d_in[6];
    const void* Wo = d_in[7];
    const void* bo = d_in[8];

    const int nnz1 = in_sizes[1] / 2;
    const int nnz2 = in_sizes[2] / 2;
    const int nblk = (nnz2 + CHUNK - 1) / CHUNK;

    // ---- workspace layout (units of 4 bytes); ws is large (~268 MB) ----
    float* ws = (float*)d_ws;
    unsigned short* xt1b = (unsigned short*)ws;              // [0 .. 640,000)
    unsigned int*   xt1u = (unsigned int*)xt1b;
    unsigned short* xt2b = (unsigned short*)(ws + 640000);   // [.. 1,280,000)
    unsigned int*   xt2u = (unsigned int*)xt2b;
    float* o      = ws + 1280000;      // 1,280,000  --- zero span start
    int*   fill1e = (int*)(ws + 2560000);   //  4,000
    int*   fill1n = (int*)(ws + 2564000);   // 10,000
    float* esum2f = ws + 2574000;           // 512,000 --- zero span end
    // zero span: [1,280,000 .. 3,086,000) = 1,806,000 floats = 451,500 f4
    int* ptr2  = (int*)(ws + 3086000);      //  4,001
    int* ptr1e = (int*)(ws + 3090004);      //  4,001
    int* ptr1n = (int*)(ws + 3094008);      // 10,001
    int* nptr  = (int*)(ws + 3104012);      // 10,001
    int* bh1e  = (int*)(ws + 3114016);      // 4 x  4,000
    int* bh1n  = (int*)(ws + 3130016);      // 4 x 10,000
    unsigned int* emean2u = (unsigned int*)(ws + 3170016);   // 256,000
    unsigned int* emean1u = (unsigned int*)(ws + 3426016);   // 256,000
    unsigned short* nodelist2 = (unsigned short*)(ws + 3682016);
    const size_t nl2u = ((size_t)nnz2 + 1) / 2;
    unsigned short* nodelist1 = (unsigned short*)(ws + 3682016 + nl2u);
    const size_t nl1u = ((size_t)nnz1 + 1) / 2;
    unsigned short* edgelist1 = (unsigned short*)(ws + 3682016 + nl2u + nl1u);
    const size_t bh_off = (3682016 + nl2u + 2 * nl1u + 7) & ~(size_t)7;
    int* bh = (int*)(ws + bh_off);

    const int segB = ((nnz2 + SEG - 1) / SEG + 3) / 4;

    // 1) mega-prep: hist2 | hist1 | gemm | zero | nptr
    prep<<<nblk + 8 + G_GEMM + G_ZERO + G_NPTR, 256, 0, stream>>>(
        x, W1, b1, W2, b2, xt1b, xt2b, idx1, nnz1, idx2, nnz2,
        nptr, (float4*)(ws + 1280000), 451500, bh, bh1e, bh1n, nblk);

    // 2) scans: ptr2 | ptr1e | ptr1n
    scans3<<<3, 256, 0, stream>>>(bh, nblk, ptr2, bh1e, ptr1e, bh1n, ptr1n);

    // 3) scan_blocks (bh -> bases) | fill_both (scale-1 lists)
    sb_fb<<<16 + (nnz1 + 255) / 256, 256, 0, stream>>>(
        ptr2, bh, nblk, idx1, nnz1, ptr1e, fill1e, nodelist1,
        ptr1n, fill1n, edgelist1);

    // 4) scale-2 placement
    place_entries<<<nblk, 256, 0, stream>>>(idx2, nnz2, bh, nodelist2);

    // 5) edge gathers: s2 segment sums | s1 wave-per-edge mean
    edge_gather<<<segB + N_EDGES / 4, 256, 0, stream>>>(
        nodelist2, ptr2, nnz2, xt2u, esum2f, segB,
        nodelist1, ptr1e, xt1u, emean1u);

    // 6) s2 mean + pack
    pack2<<<(N_EDGES * 64) / 256, 256, 0, stream>>>(esum2f, ptr2, emean2u);

    // 7) node gathers: s2 segment sums | s1 wave-per-node (both atomic on o)
    node_gather<<<segB + N_NODES / 4, 256, 0, stream>>>(
        idx2 + nnz2, nptr, nnz2, emean2u, o, segB,
        edgelist1, ptr1n, emean1u);

    // 8) output projection
    outproj<<<N_NODES / 16, 256, 0, stream>>>(o, Wo, bo, d_out,
                                              (const unsigned int*)x);
}

// Round 10
// 264.785 us; speedup vs baseline: 1.2839x; 1.2839x over previous
//
#include <hip/hip_runtime.h>
#include <hip/hip_bf16.h>

// Problem constants (fixed by the reference's setup_inputs)
#define N_NODES 10000
#define N_EDGES 4000
#define IN_CH   128
#define HOC     128   // HEADS*OUT_CH
#define OUT_CH  64
#define CHUNK   16384 // entries per counting-sort block (scale-2)
#define SEG     256   // entries per gather wave-segment (scale-2)

#define G_GEMM  625   // N_NODES/16
#define G_ZERO  512
#define G_NPTR  40    // ceil(10001/256)

__device__ __forceinline__ float bf2f(unsigned short u) {
    union { unsigned int i; float f; } v;
    v.i = ((unsigned int)u) << 16;
    return v.f;
}
__device__ __forceinline__ unsigned short f2bfu(float f) {
    union { __hip_bfloat16 h; unsigned short u; } v;
    v.h = __float2bfloat16(f);
    return v.u;
}

// load 8 consecutive float values from either fp32 or packed-bf16 storage.
__device__ __forceinline__ void load8(const void* base, size_t eoff, int isf32,
                                      float o[8]) {
    if (isf32) {
        const float4* q = (const float4*)((const float*)base + eoff);
        float4 a = q[0], b = q[1];
        o[0]=a.x; o[1]=a.y; o[2]=a.z; o[3]=a.w;
        o[4]=b.x; o[5]=b.y; o[6]=b.z; o[7]=b.w;
    } else {
        uint4 v = *(const uint4*)((const unsigned short*)base + eoff);
        const unsigned short* pv = (const unsigned short*)&v;
#pragma unroll
        for (int q = 0; q < 8; q++) o[q] = bf2f(pv[q]);
    }
}

__device__ __forceinline__ float loadS(const void* base, int i, int isf32) {
    return isf32 ? ((const float*)base)[i] : bf2f(((const unsigned short*)base)[i]);
}

// Per-wave inline dtype probe of x's first 512 bytes (L1/L2-cached; uniform
// decision per wave). 1 = fp32 storage, 0 = packed bf16.
__device__ __forceinline__ int probe_isf32(const unsigned int* __restrict__ x) {
    const int lane = threadIdx.x & 63;
    unsigned int w0 = x[lane * 2], w1 = x[lane * 2 + 1];
    int h = 0, z = 0;
    {
        unsigned int lo = w0 & 0xFFFFu;
        if (lo == 0u) z++; else if (((lo >> 7) & 0xFF) >= 0x90u) h++;
        lo = w1 & 0xFFFFu;
        if (lo == 0u) z++; else if (((lo >> 7) & 0xFF) >= 0x90u) h++;
    }
    unsigned long long bh = __ballot(h > 0);   // fp32 mantissa garbage
    unsigned long long bz = __ballot(z == 2);  // fp32 storing bf16-rounded
    return (__popcll(bh) > 8 || __popcll(bz) > 50) ? 1 : 0;
}

// ---------------------------------------------------------------------------
// MEGA-PREP: block-range fused, all roles mutually independent.
// cnt2/cnt1e/cnt1n are pre-zeroed by hipMemsetAsync BEFORE this kernel, so
// histogram roles can accumulate them atomically (distributed, cheap).
//  [0, nblk)        hist2: per-CHUNK edge histogram of idx2 -> bh + cnt2 atomics
//  [nblk, nblk+8)   hist1: LDS histograms of idx1 -> cnt1e/cnt1n atomics
//  [.., +G_GEMM)    gemm: xt1/xt2 = x@W1^T+b1 / x@W2^T+b2 (bf16 out)
//  [.., +G_ZERO)    zero: o + fill1e + fill1n + esum2f (grid-stride)
//  [.., +G_NPTR)    nptr: lower_bound(idx2, n)
__global__ __launch_bounds__(256) void prep(
    const void* __restrict__ x,
    const void* __restrict__ W1, const void* __restrict__ b1,
    const void* __restrict__ W2, const void* __restrict__ b2,
    unsigned short* __restrict__ xt1b, unsigned short* __restrict__ xt2b,
    const int* __restrict__ idx1, int nnz1,
    const int* __restrict__ idx2, int nnz2,
    int* __restrict__ nptr, float4* __restrict__ zerobase, int zeroN4,
    int* __restrict__ bh, int* __restrict__ cnt2,
    int* __restrict__ cnt1e, int* __restrict__ cnt1n, int nblk)
{
    __shared__ __align__(16) char smem[40000];
    int b = blockIdx.x;

    if (b < nblk) {                     // ---- hist2 ----
        int* h = (int*)smem;
        for (int t = threadIdx.x; t < N_EDGES; t += 256) h[t] = 0;
        __syncthreads();
        const int lo = b * CHUNK;
        const int hi = min(nnz2, lo + CHUNK);
        for (int i = lo + threadIdx.x; i < hi; i += 256)
            atomicAdd(&h[idx2[nnz2 + i]], 1);
        __syncthreads();
        int* dst = bh + (size_t)b * N_EDGES;
        for (int t = threadIdx.x; t < N_EDGES; t += 256) {
            int v = h[t];
            dst[t] = v;
            if (v) atomicAdd(&cnt2[t], v);
        }
        return;
    }
    b -= nblk;

    if (b < 8) {                        // ---- hist1 (4 edge + 4 node blocks) ----
        const int isEdge = b < 4;
        const int bid = isEdge ? b : (b - 4);
        const int nb = isEdge ? N_EDGES : N_NODES;
        const int* src = isEdge ? (idx1 + nnz1) : idx1;
        int* dst = isEdge ? cnt1e : cnt1n;
        int* h = (int*)smem;
        for (int t = threadIdx.x; t < nb; t += 256) h[t] = 0;
        __syncthreads();
        for (int i = bid * 256 + threadIdx.x; i < nnz1; i += 4 * 256)
            atomicAdd(&h[src[i]], 1);
        __syncthreads();
        for (int t = threadIdx.x; t < nb; t += 256) {
            int v = h[t];
            if (v) atomicAdd(&dst[t], v);
        }
        return;
    }
    b -= 8;

    if (b < G_GEMM) {                   // ---- gemm ----
        const int isf32 = probe_isf32((const unsigned int*)x);
        float (*xs)[IN_CH] = (float (*)[IN_CH])smem;
        const int n0 = b * 16;
        {
            float v[8];
            load8(x, (size_t)n0 * IN_CH + (size_t)threadIdx.x * 8, isf32, v);
            float* dst = &xs[0][0] + threadIdx.x * 8;
#pragma unroll
            for (int q = 0; q < 8; q++) dst[q] = v[q];
        }
        __syncthreads();

        const int sel = threadIdx.x >> 7;
        const int j   = threadIdx.x & 127;
        const void* W  = sel ? W2 : W1;
        const void* bb = sel ? b2 : b1;
        unsigned short* xt = sel ? xt2b : xt1b;

        float acc[16];
#pragma unroll
        for (int m = 0; m < 16; m++) acc[m] = 0.f;

        for (int kk = 0; kk < 16; kk++) {
            float w[8];
            load8(W, (size_t)j * IN_CH + kk * 8, isf32, w);
#pragma unroll
            for (int m = 0; m < 16; m++) {
                const float* xr = &xs[m][kk * 8];
                acc[m] += xr[0]*w[0] + xr[1]*w[1] + xr[2]*w[2] + xr[3]*w[3]
                        + xr[4]*w[4] + xr[5]*w[5] + xr[6]*w[6] + xr[7]*w[7];
            }
        }
        const float bias = loadS(bb, j, isf32);
#pragma unroll
        for (int m = 0; m < 16; m++)
            xt[(size_t)(n0 + m) * HOC + j] = f2bfu(acc[m] + bias);
        return;
    }
    b -= G_GEMM;

    if (b < G_ZERO) {                   // ---- zero (grid-stride float4) ----
        for (int t = b * 256 + threadIdx.x; t < zeroN4; t += G_ZERO * 256)
            zerobase[t] = make_float4(0.f, 0.f, 0.f, 0.f);
        return;
    }
    b -= G_ZERO;

    {                                   // ---- nptr ----
        int n = b * 256 + threadIdx.x;
        if (n > N_NODES) return;
        int lo = 0, hi = nnz2;
        while (lo < hi) { int mid = (lo + hi) >> 1; if (idx2[mid] < n) lo = mid + 1; else hi = mid; }
        nptr[n] = lo;
    }
}

// ---------------------------------------------------------------------------
// 3-block exclusive scans over the (atomically accumulated) count arrays.
//  block 0: cnt2 -> ptr2; block 1: cnt1e -> ptr1e; block 2: cnt1n -> ptr1n.
__global__ __launch_bounds__(256) void scans3(
    const int* __restrict__ cnt2, int* __restrict__ ptr2,
    const int* __restrict__ cnt1e, int* __restrict__ ptr1e,
    const int* __restrict__ cnt1n, int* __restrict__ ptr1n)
{
    const int* cnt; int* ptr; int nb;
    if (blockIdx.x == 0)      { cnt = cnt2;  ptr = ptr2;  nb = N_EDGES; }
    else if (blockIdx.x == 1) { cnt = cnt1e; ptr = ptr1e; nb = N_EDGES; }
    else                      { cnt = cnt1n; ptr = ptr1n; nb = N_NODES; }
    __shared__ int part[256];
    const int t = threadIdx.x;
    const int K = (nb + 255) >> 8;
    const int base = t * K;
    int s = 0;
    for (int q = 0; q < K; q++) {
        int i = base + q;
        s += (i < nb) ? cnt[i] : 0;
    }
    part[t] = s;
    __syncthreads();
    for (int d = 1; d < 256; d <<= 1) {
        int v = (t >= d) ? part[t - d] : 0;
        __syncthreads();
        part[t] += v;
        __syncthreads();
    }
    int run = part[t] - s;
    for (int q = 0; q < K; q++) {
        int i = base + q;
        if (i < nb) { ptr[i] = run; run += cnt[i]; }
    }
    if (t == 255) ptr[nb] = part[255];
}

// ---------------------------------------------------------------------------
// Fused: scan_blocks (bh counts -> per-block bases) + fill_both (scale-1 lists)
__global__ __launch_bounds__(256) void sb_fb(
    const int* __restrict__ ptr2, int* __restrict__ bh, int nblk,
    const int* __restrict__ idx1, int nnz1,
    const int* __restrict__ ptr1e, int* __restrict__ fill1e,
    unsigned short* __restrict__ nodelist1,
    const int* __restrict__ ptr1n, int* __restrict__ fill1n,
    unsigned short* __restrict__ edgelist1)
{
    int b = blockIdx.x;
    if (b < 16) {                       // scan_blocks: thread per edge
        int e = b * 256 + threadIdx.x;
        if (e >= N_EDGES) return;
        int run = ptr2[e];
        for (int k = 0; k < nblk; k++) {
            int i = k * N_EDGES + e;
            int t = bh[i];
            bh[i] = run;
            run += t;
        }
        return;
    }
    b -= 16;
    int i = b * 256 + threadIdx.x;
    if (i >= nnz1) return;
    int n = idx1[i];
    int e = idx1[nnz1 + i];
    int se = atomicAdd(&fill1e[e], 1);
    nodelist1[ptr1e[e] + se] = (unsigned short)n;
    int sn = atomicAdd(&fill1n[n], 1);
    edgelist1[ptr1n[n] + sn] = (unsigned short)e;
}

// ---------------------------------------------------------------------------
// scale-2 placement with LDS slot counters (no global atomics)
__global__ __launch_bounds__(256) void place_entries(
    const int* __restrict__ idx, int nnz, const int* __restrict__ bh,
    unsigned short* __restrict__ nodelist)
{
    __shared__ int lh[N_EDGES];
    for (int t = threadIdx.x; t < N_EDGES; t += 256) lh[t] = 0;
    __syncthreads();
    const int b = blockIdx.x;
    const int lo = b * CHUNK;
    const int hi = min(nnz, lo + CHUNK);
    const int* bhb = bh + (size_t)b * N_EDGES;
    for (int i = lo + threadIdx.x; i < hi; i += 256) {
        int n = idx[i];
        int e = idx[nnz + i];
        int s = atomicAdd(&lh[e], 1);
        nodelist[bhb[e] + s] = (unsigned short)n;
    }
}

// ---------------------------------------------------------------------------
// Fused edge gathers:
//  [0, segB): scale-2 segment-parallel sum into esum2f (8-wide ILP + flush)
//  [segB, segB+1000): scale-1 wave-per-edge mean (fused div+pack)
__global__ __launch_bounds__(256) void edge_gather(
    const unsigned short* __restrict__ nodelist2, const int* __restrict__ ptr2,
    int nnz2, const unsigned int* __restrict__ xt2u, float* __restrict__ esum2f,
    int segB,
    const unsigned short* __restrict__ nodelist1, const int* __restrict__ ptr1e,
    const unsigned int* __restrict__ xt1u, unsigned int* __restrict__ emean1u)
{
    const int lane = threadIdx.x & 63;
    int b = blockIdx.x;
    if (b < segB) {
        const int wave = (b * 256 + threadIdx.x) >> 6;
        const int s = wave * SEG;
        if (s >= nnz2) return;
        const int e_end = min(nnz2, s + SEG);
        int lo = 0, hi = N_EDGES;
        while (lo < hi) { int mid = (lo + hi) >> 1; if (ptr2[mid] <= s) lo = mid + 1; else hi = mid; }
        int g = lo - 1;
        int next = ptr2[g + 1];
        float accx = 0.f, accy = 0.f;
        for (int i = s; i < e_end; i += 64) {
            const int m = min(64, e_end - i);
            int vl = (i + lane < e_end) ? (int)nodelist2[i + lane] : 0;
            int j = 0;
            while (j < m) {
                while (i + j >= next) {
                    unsafeAtomicAdd(esum2f + (size_t)g * HOC + 2 * lane,     accx);
                    unsafeAtomicAdd(esum2f + (size_t)g * HOC + 2 * lane + 1, accy);
                    accx = accy = 0.f;
                    g++;
                    next = ptr2[g + 1];
                }
                int run = min(m - j, next - (i + j));
                int t = 0;
                for (; t + 7 < run; t += 8) {
                    int nn[8]; unsigned int uu[8];
#pragma unroll
                    for (int q = 0; q < 8; q++) nn[q] = __shfl(vl, j + t + q);
#pragma unroll
                    for (int q = 0; q < 8; q++) uu[q] = xt2u[nn[q] * 64 + lane];
#pragma unroll
                    for (int q = 0; q < 8; q++) {
                        accx += bf2f((unsigned short)(uu[q] & 0xFFFFu));
                        accy += bf2f((unsigned short)(uu[q] >> 16));
                    }
                }
                for (; t < run; t++) {
                    int n = __shfl(vl, j + t);
                    unsigned int u = xt2u[n * 64 + lane];
                    accx += bf2f((unsigned short)(u & 0xFFFFu));
                    accy += bf2f((unsigned short)(u >> 16));
                }
                j += run;
            }
        }
        unsafeAtomicAdd(esum2f + (size_t)g * HOC + 2 * lane,     accx);
        unsafeAtomicAdd(esum2f + (size_t)g * HOC + 2 * lane + 1, accy);
        return;
    }
    b -= segB;
    {   // scale-1 wave-per-edge mean
        const int e = b * 4 + (threadIdx.x >> 6);
        const int lo = ptr1e[e], hi = ptr1e[e + 1];
        float accx = 0.f, accy = 0.f;
        for (int base = lo; base < hi; base += 64) {
            const int m = min(64, hi - base);
            int vl = (base + lane < hi) ? (int)nodelist1[base + lane] : 0;
            int t = 0;
            for (; t + 7 < m; t += 8) {
                int nn[8]; unsigned int uu[8];
#pragma unroll
                for (int q = 0; q < 8; q++) nn[q] = __shfl(vl, t + q);
#pragma unroll
                for (int q = 0; q < 8; q++) uu[q] = xt1u[nn[q] * 64 + lane];
#pragma unroll
                for (int q = 0; q < 8; q++) {
                    accx += bf2f((unsigned short)(uu[q] & 0xFFFFu));
                    accy += bf2f((unsigned short)(uu[q] >> 16));
                }
            }
            for (; t < m; t++) {
                int n = __shfl(vl, t);
                unsigned int u = xt1u[n * 64 + lane];
                accx += bf2f((unsigned short)(u & 0xFFFFu));
                accy += bf2f((unsigned short)(u >> 16));
            }
        }
        const float inv = 1.f / fmaxf((float)(hi - lo), 1.f);
        emean1u[e * 64 + lane] =
            ((unsigned int)f2bfu(accy * inv) << 16) | f2bfu(accx * inv);
    }
}

// ---------------------------------------------------------------------------
// s2 mean + pack to bf16x2 (counts derived from ptr2 diffs)
__global__ __launch_bounds__(256) void pack2(
    const float* __restrict__ esum2f, const int* __restrict__ ptr2,
    unsigned int* __restrict__ emean2u)
{
    int t = blockIdx.x * 256 + threadIdx.x;   // t < N_EDGES*64
    int e = t >> 6;
    float inv = 1.f / fmaxf((float)(ptr2[e + 1] - ptr2[e]), 1.f);
    float2 v = *(const float2*)(esum2f + (size_t)t * 2);
    emean2u[t] = ((unsigned int)f2bfu(v.y * inv) << 16) | f2bfu(v.x * inv);
}

// ---------------------------------------------------------------------------
// Fused node gathers (both sides atomically accumulate into zeroed o):
//  [0, segB): scale-2 segment-parallel; [segB, +2500): scale-1 wave-per-node.
__global__ __launch_bounds__(256) void node_gather(
    const int* __restrict__ vals2, const int* __restrict__ nptr, int nnz2,
    const unsigned int* __restrict__ emean2u, float* __restrict__ o, int segB,
    const unsigned short* __restrict__ edgelist1, const int* __restrict__ ptr1n,
    const unsigned int* __restrict__ emean1u)
{
    const int lane = threadIdx.x & 63;
    int b = blockIdx.x;
    if (b < segB) {
        const int wave = (b * 256 + threadIdx.x) >> 6;
        const int s = wave * SEG;
        if (s >= nnz2) return;
        const int e_end = min(nnz2, s + SEG);
        int lo = 0, hi = N_NODES;
        while (lo < hi) { int mid = (lo + hi) >> 1; if (nptr[mid] <= s) lo = mid + 1; else hi = mid; }
        int g = lo - 1;
        int next = nptr[g + 1];
        float accx = 0.f, accy = 0.f;
        for (int i = s; i < e_end; i += 64) {
            const int m = min(64, e_end - i);
            int vl = (i + lane < e_end) ? vals2[i + lane] : 0;
            int j = 0;
            while (j < m) {
                while (i + j >= next) {
                    unsafeAtomicAdd(o + (size_t)g * HOC + 2 * lane,     accx);
                    unsafeAtomicAdd(o + (size_t)g * HOC + 2 * lane + 1, accy);
                    accx = accy = 0.f;
                    g++;
                    next = nptr[g + 1];
                }
                int run = min(m - j, next - (i + j));
                int t = 0;
                for (; t + 7 < run; t += 8) {
                    int ee[8]; unsigned int uu[8];
#pragma unroll
                    for (int q = 0; q < 8; q++) ee[q] = __shfl(vl, j + t + q);
#pragma unroll
                    for (int q = 0; q < 8; q++) uu[q] = emean2u[ee[q] * 64 + lane];
#pragma unroll
                    for (int q = 0; q < 8; q++) {
                        accx += bf2f((unsigned short)(uu[q] & 0xFFFFu));
                        accy += bf2f((unsigned short)(uu[q] >> 16));
                    }
                }
                for (; t < run; t++) {
                    int e = __shfl(vl, j + t);
                    unsigned int u = emean2u[e * 64 + lane];
                    accx += bf2f((unsigned short)(u & 0xFFFFu));
                    accy += bf2f((unsigned short)(u >> 16));
                }
                j += run;
            }
        }
        unsafeAtomicAdd(o + (size_t)g * HOC + 2 * lane,     accx);
        unsafeAtomicAdd(o + (size_t)g * HOC + 2 * lane + 1, accy);
        return;
    }
    b -= segB;
    {   // scale-1 wave-per-node (atomic adds; concurrent with s2 part)
        const int n = b * 4 + (threadIdx.x >> 6);
        const int lo = ptr1n[n], hi = ptr1n[n + 1];
        if (lo == hi) return;
        float accx = 0.f, accy = 0.f;
        for (int base = lo; base < hi; base += 64) {
            const int m = min(64, hi - base);
            int vl = (base + lane < hi) ? (int)edgelist1[base + lane] : 0;
            int t = 0;
            for (; t + 7 < m; t += 8) {
                int ee[8]; unsigned int uu[8];
#pragma unroll
                for (int q = 0; q < 8; q++) ee[q] = __shfl(vl, t + q);
#pragma unroll
                for (int q = 0; q < 8; q++) uu[q] = emean1u[ee[q] * 64 + lane];
#pragma unroll
                for (int q = 0; q < 8; q++) {
                    accx += bf2f((unsigned short)(uu[q] & 0xFFFFu));
                    accy += bf2f((unsigned short)(uu[q] >> 16));
                }
            }
            for (; t < m; t++) {
                int e = __shfl(vl, t);
                unsigned int u = emean1u[e * 64 + lane];
                accx += bf2f((unsigned short)(u & 0xFFFFu));
                accy += bf2f((unsigned short)(u >> 16));
            }
        }
        unsafeAtomicAdd(o + (size_t)n * HOC + 2 * lane,     accx);
        unsafeAtomicAdd(o + (size_t)n * HOC + 2 * lane + 1, accy);
    }
}

// ---------------------------------------------------------------------------
// out = 0.5*o @ Wout^T + bout  (16 nodes/block; 4 indep acc chains/thread)
__global__ __launch_bounds__(256) void outproj(
    const float* __restrict__ o, const void* __restrict__ Wout,
    const void* __restrict__ bout, void* __restrict__ out,
    const unsigned int* __restrict__ xprobe)
{
    const int isf32 = probe_isf32(xprobe);
    __shared__ float os[16][HOC];
    const int n0 = blockIdx.x * 16;
    {
        const float4* src = (const float4*)(o + (size_t)n0 * HOC);
        float4* d = (float4*)&os[0][0];
        d[threadIdx.x]       = src[threadIdx.x];
        d[threadIdx.x + 256] = src[threadIdx.x + 256];
    }
    __syncthreads();
    const int jo = threadIdx.x & 63;
    const int g  = threadIdx.x >> 6;
    float acc[4] = {0.f, 0.f, 0.f, 0.f};
    for (int kk = 0; kk < 16; kk++) {
        float w[8];
        load8(Wout, (size_t)jo * HOC + kk * 8, isf32, w);
#pragma unroll
        for (int mm = 0; mm < 4; mm++) {
            const float* xr = &os[g * 4 + mm][kk * 8];
            acc[mm] += xr[0]*w[0] + xr[1]*w[1] + xr[2]*w[2] + xr[3]*w[3]
                     + xr[4]*w[4] + xr[5]*w[5] + xr[6]*w[6] + xr[7]*w[7];
        }
    }
    const float bias = loadS(bout, jo, isf32);
#pragma unroll
    for (int mm = 0; mm < 4; mm++) {
        float r = 0.5f * acc[mm] + bias;
        size_t oi = (size_t)(n0 + g * 4 + mm) * OUT_CH + jo;
        if (isf32) ((float*)out)[oi] = r;
        else       ((__hip_bfloat16*)out)[oi] = __float2bfloat16(r);
    }
}

// ---------------------------------------------------------------------------
extern "C" void kernel_launch(void* const* d_in, const int* in_sizes, int n_in,
                              void* d_out, int out_size, void* d_ws, size_t ws_size,
                              hipStream_t stream)
{
    const void* x  = d_in[0];
    const int* idx1 = (const int*)d_in[1];
    const int* idx2 = (const int*)d_in[2];
    const void* W1 = d_in[3];
    const void* b1 = d_in[4];
    const void* W2 = d_in[5];
    const void* b2 = d_in[6];
    const void* Wo = d_in[7];
    const void* bo = d_in[8];

    const int nnz1 = in_sizes[1] / 2;
    const int nnz2 = in_sizes[2] / 2;
    const int nblk = (nnz2 + CHUNK - 1) / CHUNK;

    // ---- workspace layout (units of 4 bytes); ws is large (~268 MB) ----
    float* ws = (float*)d_ws;
    unsigned short* xt1b = (unsigned short*)ws;              // [0 .. 640,000)
    unsigned int*   xt1u = (unsigned int*)xt1b;
    unsigned short* xt2b = (unsigned short*)(ws + 640000);   // [.. 1,280,000)
    unsigned int*   xt2u = (unsigned int*)xt2b;
    float* o      = ws + 1280000;      // 1,280,000  --- zero span start
    int*   fill1e = (int*)(ws + 2560000);   //  4,000
    int*   fill1n = (int*)(ws + 2564000);   // 10,000
    float* esum2f = ws + 2574000;           // 512,000 --- zero span end
    // zero span (prep): [1,280,000 .. 3,086,000) = 451,500 f4
    // memset span (host-side memsetAsync): cnt2+cnt1e+cnt1n = 18,000 ints
    int* cnt2  = (int*)(ws + 3086000);      //  4,000
    int* cnt1e = (int*)(ws + 3090000);      //  4,000
    int* cnt1n = (int*)(ws + 3094000);      // 10,000
    int* ptr2  = (int*)(ws + 3104000);      //  4,001
    int* ptr1e = (int*)(ws + 3108004);      //  4,001
    int* ptr1n = (int*)(ws + 3112008);      // 10,001
    int* nptr  = (int*)(ws + 3122012);      // 10,001
    unsigned int* emean2u = (unsigned int*)(ws + 3132016);   // 256,000
    unsigned int* emean1u = (unsigned int*)(ws + 3388016);   // 256,000
    unsigned short* nodelist2 = (unsigned short*)(ws + 3644016);
    const size_t nl2u = ((size_t)nnz2 + 1) / 2;
    unsigned short* nodelist1 = (unsigned short*)(ws + 3644016 + nl2u);
    const size_t nl1u = ((size_t)nnz1 + 1) / 2;
    unsigned short* edgelist1 = (unsigned short*)(ws + 3644016 + nl2u + nl1u);
    const size_t bh_off = (3644016 + nl2u + 2 * nl1u + 7) & ~(size_t)7;
    int* bh = (int*)(ws + bh_off);

    const int segB = ((nnz2 + SEG - 1) / SEG + 3) / 4;

    // 0) zero the count arrays (graph-capture-safe async memset)
    hipMemsetAsync(cnt2, 0, 18000 * sizeof(int), stream);

    // 1) mega-prep: hist2 | hist1 | gemm | zero | nptr
    prep<<<nblk + 8 + G_GEMM + G_ZERO + G_NPTR, 256, 0, stream>>>(
        x, W1, b1, W2, b2, xt1b, xt2b, idx1, nnz1, idx2, nnz2,
        nptr, (float4*)(ws + 1280000), 451500, bh, cnt2, cnt1e, cnt1n, nblk);

    // 2) scans: ptr2 | ptr1e | ptr1n
    scans3<<<3, 256, 0, stream>>>(cnt2, ptr2, cnt1e, ptr1e, cnt1n, ptr1n);

    // 3) scan_blocks (bh -> bases) | fill_both (scale-1 lists)
    sb_fb<<<16 + (nnz1 + 255) / 256, 256, 0, stream>>>(
        ptr2, bh, nblk, idx1, nnz1, ptr1e, fill1e, nodelist1,
        ptr1n, fill1n, edgelist1);

    // 4) scale-2 placement
    place_entries<<<nblk, 256, 0, stream>>>(idx2, nnz2, bh, nodelist2);

    // 5) edge gathers: s2 segment sums | s1 wave-per-edge mean
    edge_gather<<<segB + N_EDGES / 4, 256, 0, stream>>>(
        nodelist2, ptr2, nnz2, xt2u, esum2f, segB,
        nodelist1, ptr1e, xt1u, emean1u);

    // 6) s2 mean + pack
    pack2<<<(N_EDGES * 64) / 256, 256, 0, stream>>>(esum2f, ptr2, emean2u);

    // 7) node gathers: s2 segment sums | s1 wave-per-node (both atomic on o)
    node_gather<<<segB + N_NODES / 4, 256, 0, stream>>>(
        idx2 + nnz2, nptr, nnz2, emean2u, o, segB,
        edgelist1, ptr1n, emean1u);

    // 8) output projection
    outproj<<<N_NODES / 16, 256, 0, stream>>>(o, Wo, bo, d_out,
                                              (const unsigned int*)x);
}